// Round 3
// baseline (180.648 us; speedup 1.0000x reference)
//
#include <hip/hip_runtime.h>

#define N_NODES 2048
#define N_EDGES 65536
#define NV 6
#define C 32
#define BLK 256

// ---------------------------------------------------------------------------
// R17 = R16 + edge23 atomic drain-at-end.
// Theory: vmcnt drains IN ORDER, so each group's 8 contended atomicAdds
// (issued mid-loop) block the next group's ea/dst loads behind their L2
// round-trip acks (~500-1000 cyc under 32-way dst collisions); at 2
// waves/SIMD that stall is unhidden, 4x per wave. Fix: reduce each group's
// accs into accr[32] (statically indexed regs, +24 VGPR ~= 214 < 256 cap,
// still 2 waves/SIMD), issue all 32 atomics once at kernel end.
// ws layout (floats): cnt[2048] | sum1|sum2|sum3 [65536 each] | h1|h2|h3.
// Locked-in lessons (all measured):
//   - atomic scatter > CSR/msg/gather structures (R3 +100, R9 +28, R12 +43)
//   - cooperative grid.sync ~50us each on 8 XCDs -> mega-kernel +365 (R7)
//   - reg-W core needs its natural ~190 VGPR; capping to 3 waves spills (R11)
//   - split-i duplicates per-edge fixed costs, +9.2 us (R14)
//   - R15 dst-hoist + full-wave-atomic rewrite: +12 us (reverted)
//   - cbt-sym + node-f4: neutral (R16), kept at no cost
// ---------------------------------------------------------------------------

// Layer 1 (in_c = 1), degree count fused (o==0 lane), sum2/3 zeroing fused.
__global__ void edge1_kernel(const float* __restrict__ x,
                             const float* __restrict__ ea,
                             const int* __restrict__ src,
                             const int* __restrict__ dst,
                             const float* __restrict__ W1,
                             const float* __restrict__ b1,
                             float* __restrict__ sum1,
                             float* __restrict__ sum23,   // sum2 base (2*N*C floats)
                             float* __restrict__ cnt) {
    int t = blockIdx.x * blockDim.x + threadIdx.x;
    if (t < 2 * N_NODES * C) sum23[t] = 0.0f;   // zero sum2+sum3
    int e = t >> 5, o = t & 31;
    if (e >= N_EDGES) return;
    const float* eap = ea + e * NV;
    float w = b1[o];
#pragma unroll
    for (int v = 0; v < NV; v++) w = fmaf(eap[v], W1[v * C + o], w);
    w = fmaxf(w, 0.0f);
    int d = dst[e];
    atomicAdd(&sum1[d * C + o], x[src[e]] * w);
    if (o == 0) atomicAdd(&cnt[d], 1.0f);
}

// Finalize a layer: h_out = relu(sum/max(cnt,1) + h_prev @ root + bias)
template <int IN_C>
__global__ void node_kernel(const float* __restrict__ sum,
                            const float* __restrict__ cnt,
                            const float* __restrict__ hprev,
                            const float* __restrict__ root,  // [IN_C, C]
                            const float* __restrict__ bias,  // [C]
                            float* __restrict__ hout) {
    int t = blockIdx.x * blockDim.x + threadIdx.x;  // N*C threads
    int n = t >> 5, o = t & 31;
    float inv = 1.0f / fmaxf(cnt[n], 1.0f);
    float acc = sum[t] * inv + bias[o];
    if constexpr (IN_C == 1) {
        acc = fmaf(hprev[n], root[o], acc);
    } else {
        const float4* hp4 = (const float4*)(hprev + n * IN_C);
#pragma unroll
        for (int q = 0; q < IN_C / 4; q++) {
            float4 hv = hp4[q];
            acc = fmaf(hv.x, root[(q * 4 + 0) * C + o], acc);
            acc = fmaf(hv.y, root[(q * 4 + 1) * C + o], acc);
            acc = fmaf(hv.z, root[(q * 4 + 2) * C + o], acc);
            acc = fmaf(hv.w, root[(q * 4 + 3) * C + o], acc);
        }
    }
    hout[t] = fmaxf(acc, 0.0f);
}

// Layers 2/3: R10/R13 reg-W core + up-front 4-group h staging.
// R17: group loop fully unrolled, accs reduced into accr[32] (static idx),
// ALL atomics + dst loads moved to a single epilogue after the loop -- no
// vmem op in the loop tail to queue loads behind atomic acks.
__global__ __launch_bounds__(BLK, 2) void edge23_kernel(
    const float* __restrict__ hprev,   // [N, 32]
    const float* __restrict__ ea,      // [E, 6]
    const int* __restrict__ src,
    const int* __restrict__ dst,
    const float* __restrict__ W,       // [NV, 1024]
    const float* __restrict__ b,       // [1024]
    float* __restrict__ sumout)        // [N, 32]
{
    __shared__ float hb[4][4][256];    // [wave][group][...] = 16 KB
    const int lane = threadIdx.x & 63;
    const int o = lane & 31;
    const int half = lane >> 5;
    const int i0 = half * 16;
    const int w = threadIdx.x >> 6;

    float wreg[16][6], breg[16];
#pragma unroll
    for (int j = 0; j < 16; j++) {
#pragma unroll
        for (int v = 0; v < 6; v++) wreg[j][v] = W[v * 1024 + (i0 + j) * C + o];
        breg[j] = b[(i0 + j) * C + o];
    }

    const int wid = (blockIdx.x * BLK + threadIdx.x) >> 6;  // 0..2047

    // ---- stage h[src] for all 4 groups up front ----
    int4 sqs[4];
#pragma unroll
    for (int i = 0; i < 4; i++)
        sqs[i] = *(const int4*)&src[(wid + i * 2048) * 8 + half * 4];
#pragma unroll
    for (int i = 0; i < 4; i++) {
        float4 hq;
        hq.x = hprev[sqs[i].x * C + o];
        hq.y = hprev[sqs[i].y * C + o];
        hq.z = hprev[sqs[i].z * C + o];
        hq.w = hprev[sqs[i].w * C + o];
        *(float4*)&hb[w][i][half * 128 + o * 4] = hq;  // contiguous 1KB wave write
    }

    float accr[32];                    // reduced accs, statically indexed
#pragma unroll
    for (int i = 0; i < 4; i++) {
        const int e0 = (wid + i * 2048) * 8;
        const float* hbw = &hb[w][i][0];
        const float4* eap4 = (const float4*)(ea + (size_t)e0 * NV);
        float accs[8];
#pragma unroll
        for (int sub = 0; sub < 2; sub++) {
            float eaf[24];
#pragma unroll
            for (int t = 0; t < 6; t++) *(float4*)&eaf[t * 4] = eap4[sub * 6 + t];
            float a0 = 0.0f, a1 = 0.0f, a2 = 0.0f, a3 = 0.0f;
#pragma unroll
            for (int j = 0; j < 16; j++) {
                const float4 hA = *(const float4*)&hbw[sub * 128 + (i0 + j) * 4];
                const float bb = breg[j];
                const float w0 = wreg[j][0], w1 = wreg[j][1], w2 = wreg[j][2];
                const float w3 = wreg[j][3], w4 = wreg[j][4], w5 = wreg[j][5];
                float t0 = bb, t1 = bb, t2 = bb, t3 = bb;
                t0 = fmaf(eaf[0],  w0, t0); t1 = fmaf(eaf[6],  w0, t1);
                t2 = fmaf(eaf[12], w0, t2); t3 = fmaf(eaf[18], w0, t3);
                t0 = fmaf(eaf[1],  w1, t0); t1 = fmaf(eaf[7],  w1, t1);
                t2 = fmaf(eaf[13], w1, t2); t3 = fmaf(eaf[19], w1, t3);
                t0 = fmaf(eaf[2],  w2, t0); t1 = fmaf(eaf[8],  w2, t1);
                t2 = fmaf(eaf[14], w2, t2); t3 = fmaf(eaf[20], w2, t3);
                t0 = fmaf(eaf[3],  w3, t0); t1 = fmaf(eaf[9],  w3, t1);
                t2 = fmaf(eaf[15], w3, t2); t3 = fmaf(eaf[21], w3, t3);
                t0 = fmaf(eaf[4],  w4, t0); t1 = fmaf(eaf[10], w4, t1);
                t2 = fmaf(eaf[16], w4, t2); t3 = fmaf(eaf[22], w4, t3);
                t0 = fmaf(eaf[5],  w5, t0); t1 = fmaf(eaf[11], w5, t1);
                t2 = fmaf(eaf[17], w5, t2); t3 = fmaf(eaf[23], w5, t3);
                a0 = fmaf(hA.x, fmaxf(t0, 0.0f), a0);
                a1 = fmaf(hA.y, fmaxf(t1, 0.0f), a1);
                a2 = fmaf(hA.z, fmaxf(t2, 0.0f), a2);
                a3 = fmaf(hA.w, fmaxf(t3, 0.0f), a3);
            }
            accs[sub * 4 + 0] = a0; accs[sub * 4 + 1] = a1;
            accs[sub * 4 + 2] = a2; accs[sub * 4 + 3] = a3;
        }
#pragma unroll
        for (int k = 0; k < 8; k++) {
            accs[k] += __shfl_down(accs[k], 32);
            accr[i * 8 + k] = accs[k];
        }
    }

    // ---- single atomic epilogue: nothing queues behind these acks ----
    if (lane < 32) {
#pragma unroll
        for (int i = 0; i < 4; i++) {
            const int e0 = (wid + i * 2048) * 8;
            const int4 dA = *(const int4*)&dst[e0];
            const int4 dB = *(const int4*)&dst[e0 + 4];
            atomicAdd(&sumout[dA.x * C + o], accr[i * 8 + 0]);
            atomicAdd(&sumout[dA.y * C + o], accr[i * 8 + 1]);
            atomicAdd(&sumout[dA.z * C + o], accr[i * 8 + 2]);
            atomicAdd(&sumout[dA.w * C + o], accr[i * 8 + 3]);
            atomicAdd(&sumout[dB.x * C + o], accr[i * 8 + 4]);
            atomicAdd(&sumout[dB.y * C + o], accr[i * 8 + 5]);
            atomicAdd(&sumout[dB.z * C + o], accr[i * 8 + 6]);
            atomicAdd(&sumout[dB.w * C + o], accr[i * 8 + 7]);
        }
    }
}

// CBT: out[i,j] = sum_k |h[i,k]-h[j,k]|. Symmetric: compute upper triangle
// (by <= bx) only, mirror off-diagonal tiles via LDS transpose.
__global__ __launch_bounds__(BLK) void cbt_kernel(const float* __restrict__ h,
                                                  float* __restrict__ out) {
    const int bx = blockIdx.x, by = blockIdx.y;
    if (by > bx) return;                 // lower-triangle blocks: mirrored instead
    __shared__ float hj_s[64][33];
    __shared__ float hi_s[64 * 32];
    __shared__ float tile[64][65];       // +1 pad: conflict-free transposed read
    const int lane = threadIdx.x & 63;
    const int w = threadIdx.x >> 6;
    const int j0 = bx * 64;
    const int i0 = by * 64;
    for (int t = threadIdx.x; t < 64 * 32; t += BLK) {
        hj_s[t >> 5][t & 31] = h[j0 * 32 + t];
        hi_s[t] = h[i0 * 32 + t];
    }
    __syncthreads();
    float hj[32];
#pragma unroll
    for (int k = 0; k < 32; k++) hj[k] = hj_s[lane][k];
    const int j = j0 + lane;
#pragma unroll 4
    for (int ii = w * 16; ii < w * 16 + 16; ii++) {
        float acc = 0.0f;
#pragma unroll
        for (int k = 0; k < 32; k++) acc += fabsf(hi_s[ii * 32 + k] - hj[k]);
        out[(size_t)(i0 + ii) * N_NODES + j] = acc;
        tile[ii][lane] = acc;            // row write, lanes consecutive: no conflict
    }
    if (by == bx) return;                // diagonal tile is its own transpose
    __syncthreads();
#pragma unroll 4
    for (int k = 0; k < 16; k++) {
        const int jj = w * 16 + k;
        // out[j0+jj][i0+lane] = cbt(i0+lane, j0+jj) = tile[lane][jj]
        // LDS: stride 65 between lanes -> bank = (lane+jj)%32, 2-way = free
        out[(size_t)(j0 + jj) * N_NODES + i0 + lane] = tile[lane][jj];
    }
}

extern "C" void kernel_launch(void* const* d_in, const int* in_sizes, int n_in,
                              void* d_out, int out_size, void* d_ws, size_t ws_size,
                              hipStream_t stream) {
    const float* x         = (const float*)d_in[0];
    const float* edge_attr = (const float*)d_in[1];
    const int*   edge_idx  = (const int*)d_in[2];
    const float* W1 = (const float*)d_in[3];
    const float* b1 = (const float*)d_in[4];
    const float* root1 = (const float*)d_in[5];
    const float* bias1 = (const float*)d_in[6];
    const float* W2 = (const float*)d_in[7];
    const float* b2 = (const float*)d_in[8];
    const float* root2 = (const float*)d_in[9];
    const float* bias2 = (const float*)d_in[10];
    const float* W3 = (const float*)d_in[11];
    const float* b3 = (const float*)d_in[12];
    const float* root3 = (const float*)d_in[13];
    const float* bias3 = (const float*)d_in[14];

    const int* src = edge_idx;            // row 0
    const int* dst = edge_idx + N_EDGES;  // row 1

    float* ws   = (float*)d_ws;
    float* cnt  = ws;
    float* sum1 = ws + N_NODES;
    float* sum2 = sum1 + N_NODES * C;
    float* sum3 = sum2 + N_NODES * C;
    float* h1   = sum3 + N_NODES * C;
    float* h2   = h1 + N_NODES * C;
    float* h3   = h2 + N_NODES * C;

    // zero cnt + sum1 only (270 KB); sum2/sum3 zeroed inside edge1
    hipMemsetAsync(d_ws, 0, (size_t)(N_NODES + N_NODES * C) * sizeof(float), stream);

    // Layer 1 (degree count + sum2/3 zeroing fused)
    edge1_kernel<<<(N_EDGES * C) / BLK, BLK, 0, stream>>>(x, edge_attr, src, dst,
                                                          W1, b1, sum1, sum2, cnt);
    node_kernel<1><<<(N_NODES * C) / BLK, BLK, 0, stream>>>(sum1, cnt, x, root1, bias1, h1);

    // Layer 2
    edge23_kernel<<<512, BLK, 0, stream>>>(h1, edge_attr, src, dst, W2, b2, sum2);
    node_kernel<C><<<(N_NODES * C) / BLK, BLK, 0, stream>>>(sum2, cnt, h1, root2, bias2, h2);

    // Layer 3
    edge23_kernel<<<512, BLK, 0, stream>>>(h2, edge_attr, src, dst, W3, b3, sum3);
    node_kernel<C><<<(N_NODES * C) / BLK, BLK, 0, stream>>>(sum3, cnt, h2, root3, bias3, h3);

    // CBT (symmetric: 528 upper-triangle tiles computed, 496 mirrored)
    cbt_kernel<<<dim3(N_NODES / 64, N_NODES / 64), BLK, 0, stream>>>(h3, (float*)d_out);
}

// Round 4
// 179.052 us; speedup vs baseline: 1.0089x; 1.0089x over previous
//
#include <hip/hip_runtime.h>

#define N_NODES 2048
#define N_EDGES 65536
#define NV 6
#define C 32
#define BLK 256

// ---------------------------------------------------------------------------
// R18 = R16 (measured 167.2) + node3 folded into cbt.
//   - edge23: byte-identical to R16/R10/R13 measured-best. FROZEN: two
//     restructures (R15 dst-hoist, R17 accr[32] drain-at-end) each cost
//     +13 us -- any live-state growth across the group loop tips the ~190
//     VGPR knife edge.
//   - cbt: recomputes h3 rows block-locally from sum3/cnt/h2/root3/bias3
//     with node_kernel's exact FMA order (bit-identical h3), so the node3
//     dispatch + h3 round-trip are deleted. Triangular 528-block grid
//     (no 496 early-return blocks).
// ws layout (floats): cnt[2048] | sum1|sum2|sum3 [65536 each] | h1|h2|h3(unused).
// Locked-in lessons (all measured):
//   - atomic scatter > CSR/msg/gather structures (R3 +100, R9 +28, R12 +43)
//   - cooperative grid.sync ~50us each on 8 XCDs -> mega-kernel +365 (R7)
//   - reg-W core needs its natural ~190 VGPR; capping to 3 waves spills (R11)
//   - split-i duplicates per-edge fixed costs, +9.2 us (R14)
//   - edge23 tail restructures: R15 +12, R17 +13 (both reverted) -- FROZEN
//   - cbt-sym + node-f4: neutral (R16), kept at no cost
// ---------------------------------------------------------------------------

// Layer 1 (in_c = 1), degree count fused (o==0 lane), sum2/3 zeroing fused.
__global__ void edge1_kernel(const float* __restrict__ x,
                             const float* __restrict__ ea,
                             const int* __restrict__ src,
                             const int* __restrict__ dst,
                             const float* __restrict__ W1,
                             const float* __restrict__ b1,
                             float* __restrict__ sum1,
                             float* __restrict__ sum23,   // sum2 base (2*N*C floats)
                             float* __restrict__ cnt) {
    int t = blockIdx.x * blockDim.x + threadIdx.x;
    if (t < 2 * N_NODES * C) sum23[t] = 0.0f;   // zero sum2+sum3
    int e = t >> 5, o = t & 31;
    if (e >= N_EDGES) return;
    const float* eap = ea + e * NV;
    float w = b1[o];
#pragma unroll
    for (int v = 0; v < NV; v++) w = fmaf(eap[v], W1[v * C + o], w);
    w = fmaxf(w, 0.0f);
    int d = dst[e];
    atomicAdd(&sum1[d * C + o], x[src[e]] * w);
    if (o == 0) atomicAdd(&cnt[d], 1.0f);
}

// Finalize a layer: h_out = relu(sum/max(cnt,1) + h_prev @ root + bias)
template <int IN_C>
__global__ void node_kernel(const float* __restrict__ sum,
                            const float* __restrict__ cnt,
                            const float* __restrict__ hprev,
                            const float* __restrict__ root,  // [IN_C, C]
                            const float* __restrict__ bias,  // [C]
                            float* __restrict__ hout) {
    int t = blockIdx.x * blockDim.x + threadIdx.x;  // N*C threads
    int n = t >> 5, o = t & 31;
    float inv = 1.0f / fmaxf(cnt[n], 1.0f);
    float acc = sum[t] * inv + bias[o];
    if constexpr (IN_C == 1) {
        acc = fmaf(hprev[n], root[o], acc);
    } else {
        const float4* hp4 = (const float4*)(hprev + n * IN_C);
#pragma unroll
        for (int q = 0; q < IN_C / 4; q++) {
            float4 hv = hp4[q];
            acc = fmaf(hv.x, root[(q * 4 + 0) * C + o], acc);
            acc = fmaf(hv.y, root[(q * 4 + 1) * C + o], acc);
            acc = fmaf(hv.z, root[(q * 4 + 2) * C + o], acc);
            acc = fmaf(hv.w, root[(q * 4 + 3) * C + o], acc);
        }
    }
    hout[t] = fmaxf(acc, 0.0f);
}

// Layers 2/3: EXACT R10/R13 measured-best body (FROZEN -- see header).
__global__ __launch_bounds__(BLK, 2) void edge23_kernel(
    const float* __restrict__ hprev,   // [N, 32]
    const float* __restrict__ ea,      // [E, 6]
    const int* __restrict__ src,
    const int* __restrict__ dst,
    const float* __restrict__ W,       // [NV, 1024]
    const float* __restrict__ b,       // [1024]
    float* __restrict__ sumout)        // [N, 32]
{
    __shared__ float hb[4][4][256];    // [wave][group][...] = 16 KB
    const int lane = threadIdx.x & 63;
    const int o = lane & 31;
    const int half = lane >> 5;
    const int i0 = half * 16;
    const int w = threadIdx.x >> 6;

    float wreg[16][6], breg[16];
#pragma unroll
    for (int j = 0; j < 16; j++) {
#pragma unroll
        for (int v = 0; v < 6; v++) wreg[j][v] = W[v * 1024 + (i0 + j) * C + o];
        breg[j] = b[(i0 + j) * C + o];
    }

    const int wid = (blockIdx.x * BLK + threadIdx.x) >> 6;  // 0..2047

    // ---- stage h[src] for all 4 groups up front ----
    int4 sqs[4];
#pragma unroll
    for (int i = 0; i < 4; i++)
        sqs[i] = *(const int4*)&src[(wid + i * 2048) * 8 + half * 4];
#pragma unroll
    for (int i = 0; i < 4; i++) {
        float4 hq;
        hq.x = hprev[sqs[i].x * C + o];
        hq.y = hprev[sqs[i].y * C + o];
        hq.z = hprev[sqs[i].z * C + o];
        hq.w = hprev[sqs[i].w * C + o];
        *(float4*)&hb[w][i][half * 128 + o * 4] = hq;  // contiguous 1KB wave write
    }

#pragma unroll 2
    for (int i = 0; i < 4; i++) {
        const int e0 = (wid + i * 2048) * 8;
        const float* hbw = &hb[w][i][0];
        const float4* eap4 = (const float4*)(ea + (size_t)e0 * NV);
        float accs[8];
#pragma unroll
        for (int sub = 0; sub < 2; sub++) {
            float eaf[24];
#pragma unroll
            for (int t = 0; t < 6; t++) *(float4*)&eaf[t * 4] = eap4[sub * 6 + t];
            float a0 = 0.0f, a1 = 0.0f, a2 = 0.0f, a3 = 0.0f;
#pragma unroll
            for (int j = 0; j < 16; j++) {
                const float4 hA = *(const float4*)&hbw[sub * 128 + (i0 + j) * 4];
                const float bb = breg[j];
                const float w0 = wreg[j][0], w1 = wreg[j][1], w2 = wreg[j][2];
                const float w3 = wreg[j][3], w4 = wreg[j][4], w5 = wreg[j][5];
                float t0 = bb, t1 = bb, t2 = bb, t3 = bb;
                t0 = fmaf(eaf[0],  w0, t0); t1 = fmaf(eaf[6],  w0, t1);
                t2 = fmaf(eaf[12], w0, t2); t3 = fmaf(eaf[18], w0, t3);
                t0 = fmaf(eaf[1],  w1, t0); t1 = fmaf(eaf[7],  w1, t1);
                t2 = fmaf(eaf[13], w1, t2); t3 = fmaf(eaf[19], w1, t3);
                t0 = fmaf(eaf[2],  w2, t0); t1 = fmaf(eaf[8],  w2, t1);
                t2 = fmaf(eaf[14], w2, t2); t3 = fmaf(eaf[20], w2, t3);
                t0 = fmaf(eaf[3],  w3, t0); t1 = fmaf(eaf[9],  w3, t1);
                t2 = fmaf(eaf[15], w3, t2); t3 = fmaf(eaf[21], w3, t3);
                t0 = fmaf(eaf[4],  w4, t0); t1 = fmaf(eaf[10], w4, t1);
                t2 = fmaf(eaf[16], w4, t2); t3 = fmaf(eaf[22], w4, t3);
                t0 = fmaf(eaf[5],  w5, t0); t1 = fmaf(eaf[11], w5, t1);
                t2 = fmaf(eaf[17], w5, t2); t3 = fmaf(eaf[23], w5, t3);
                a0 = fmaf(hA.x, fmaxf(t0, 0.0f), a0);
                a1 = fmaf(hA.y, fmaxf(t1, 0.0f), a1);
                a2 = fmaf(hA.z, fmaxf(t2, 0.0f), a2);
                a3 = fmaf(hA.w, fmaxf(t3, 0.0f), a3);
            }
            accs[sub * 4 + 0] = a0; accs[sub * 4 + 1] = a1;
            accs[sub * 4 + 2] = a2; accs[sub * 4 + 3] = a3;
        }
#pragma unroll
        for (int k = 0; k < 8; k++) accs[k] += __shfl_down(accs[k], 32);

        const int4 dA = *(const int4*)&dst[e0];
        const int4 dB = *(const int4*)&dst[e0 + 4];
        if (lane < 32) {
            atomicAdd(&sumout[dA.x * C + o], accs[0]);
            atomicAdd(&sumout[dA.y * C + o], accs[1]);
            atomicAdd(&sumout[dA.z * C + o], accs[2]);
            atomicAdd(&sumout[dA.w * C + o], accs[3]);
            atomicAdd(&sumout[dB.x * C + o], accs[4]);
            atomicAdd(&sumout[dB.y * C + o], accs[5]);
            atomicAdd(&sumout[dB.z * C + o], accs[6]);
            atomicAdd(&sumout[dB.w * C + o], accs[7]);
        }
    }
}

// CBT with node3 fused: recompute h3 rows block-locally (bit-identical to
// node_kernel<32>: acc = sum*inv + bias, then ascending-i float4 FMA).
// Triangular grid: 528 blocks, L -> (bx, by<=bx). out[i,j] = L1(h3_i, h3_j);
// mirror off-diagonal tiles via LDS transpose.
__global__ __launch_bounds__(BLK) void cbt_kernel(const float* __restrict__ sum3,
                                                  const float* __restrict__ cnt,
                                                  const float* __restrict__ h2,
                                                  const float* __restrict__ root3,
                                                  const float* __restrict__ bias3,
                                                  float* __restrict__ out) {
    const int L = blockIdx.x;
    int bx = (int)((sqrtf(8.0f * L + 1.0f) - 1.0f) * 0.5f);
    while ((bx + 1) * (bx + 2) / 2 <= L) bx++;
    while (bx * (bx + 1) / 2 > L) bx--;
    const int by = L - bx * (bx + 1) / 2;   // by <= bx

    __shared__ float hj_s[64][33];
    __shared__ float hi_s[64 * 32];
    __shared__ float tile[64][65];       // +1 pad: conflict-free transposed read
    const int lane = threadIdx.x & 63;
    const int w = threadIdx.x >> 6;
    const int j0 = bx * 64;
    const int i0 = by * 64;

    // ---- recompute h3 for the 64 j-rows and 64 i-rows ----
    // elem = threadIdx.x + r*256 covers 64 rows x 32 cols; threads 0-31 share
    // a row (h2 row broadcast, sum3/root3 coalesced).
#pragma unroll
    for (int r = 0; r < 8; r++) {
        const int elem = threadIdx.x + r * 256;  // 0..2047
        const int n = elem >> 5, o = elem & 31;
        {   // j-side row
            const int ng = j0 + n;
            const float inv = 1.0f / fmaxf(cnt[ng], 1.0f);
            float acc = sum3[ng * 32 + o] * inv + bias3[o];
            const float4* hp4 = (const float4*)(h2 + ng * 32);
#pragma unroll
            for (int q = 0; q < 8; q++) {
                float4 hv = hp4[q];
                acc = fmaf(hv.x, root3[(q * 4 + 0) * 32 + o], acc);
                acc = fmaf(hv.y, root3[(q * 4 + 1) * 32 + o], acc);
                acc = fmaf(hv.z, root3[(q * 4 + 2) * 32 + o], acc);
                acc = fmaf(hv.w, root3[(q * 4 + 3) * 32 + o], acc);
            }
            hj_s[n][o] = fmaxf(acc, 0.0f);
        }
        {   // i-side row (diagonal blocks recompute same values: harmless)
            const int ng = i0 + n;
            const float inv = 1.0f / fmaxf(cnt[ng], 1.0f);
            float acc = sum3[ng * 32 + o] * inv + bias3[o];
            const float4* hp4 = (const float4*)(h2 + ng * 32);
#pragma unroll
            for (int q = 0; q < 8; q++) {
                float4 hv = hp4[q];
                acc = fmaf(hv.x, root3[(q * 4 + 0) * 32 + o], acc);
                acc = fmaf(hv.y, root3[(q * 4 + 1) * 32 + o], acc);
                acc = fmaf(hv.z, root3[(q * 4 + 2) * 32 + o], acc);
                acc = fmaf(hv.w, root3[(q * 4 + 3) * 32 + o], acc);
            }
            hi_s[n * 32 + o] = fmaxf(acc, 0.0f);
        }
    }
    __syncthreads();

    float hj[32];
#pragma unroll
    for (int k = 0; k < 32; k++) hj[k] = hj_s[lane][k];
    const int j = j0 + lane;
#pragma unroll 4
    for (int ii = w * 16; ii < w * 16 + 16; ii++) {
        float acc = 0.0f;
#pragma unroll
        for (int k = 0; k < 32; k++) acc += fabsf(hi_s[ii * 32 + k] - hj[k]);
        out[(size_t)(i0 + ii) * N_NODES + j] = acc;
        tile[ii][lane] = acc;            // row write, lanes consecutive: no conflict
    }
    if (by == bx) return;                // diagonal tile is its own transpose
    __syncthreads();
#pragma unroll 4
    for (int k = 0; k < 16; k++) {
        const int jj = w * 16 + k;
        // out[j0+jj][i0+lane] = cbt(i0+lane, j0+jj) = tile[lane][jj]
        out[(size_t)(j0 + jj) * N_NODES + i0 + lane] = tile[lane][jj];
    }
}

extern "C" void kernel_launch(void* const* d_in, const int* in_sizes, int n_in,
                              void* d_out, int out_size, void* d_ws, size_t ws_size,
                              hipStream_t stream) {
    const float* x         = (const float*)d_in[0];
    const float* edge_attr = (const float*)d_in[1];
    const int*   edge_idx  = (const int*)d_in[2];
    const float* W1 = (const float*)d_in[3];
    const float* b1 = (const float*)d_in[4];
    const float* root1 = (const float*)d_in[5];
    const float* bias1 = (const float*)d_in[6];
    const float* W2 = (const float*)d_in[7];
    const float* b2 = (const float*)d_in[8];
    const float* root2 = (const float*)d_in[9];
    const float* bias2 = (const float*)d_in[10];
    const float* W3 = (const float*)d_in[11];
    const float* b3 = (const float*)d_in[12];
    const float* root3 = (const float*)d_in[13];
    const float* bias3 = (const float*)d_in[14];

    const int* src = edge_idx;            // row 0
    const int* dst = edge_idx + N_EDGES;  // row 1

    float* ws   = (float*)d_ws;
    float* cnt  = ws;
    float* sum1 = ws + N_NODES;
    float* sum2 = sum1 + N_NODES * C;
    float* sum3 = sum2 + N_NODES * C;
    float* h1   = sum3 + N_NODES * C;
    float* h2   = h1 + N_NODES * C;

    // zero cnt + sum1 only (270 KB); sum2/sum3 zeroed inside edge1
    hipMemsetAsync(d_ws, 0, (size_t)(N_NODES + N_NODES * C) * sizeof(float), stream);

    // Layer 1 (degree count + sum2/3 zeroing fused)
    edge1_kernel<<<(N_EDGES * C) / BLK, BLK, 0, stream>>>(x, edge_attr, src, dst,
                                                          W1, b1, sum1, sum2, cnt);
    node_kernel<1><<<(N_NODES * C) / BLK, BLK, 0, stream>>>(sum1, cnt, x, root1, bias1, h1);

    // Layer 2
    edge23_kernel<<<512, BLK, 0, stream>>>(h1, edge_attr, src, dst, W2, b2, sum2);
    node_kernel<C><<<(N_NODES * C) / BLK, BLK, 0, stream>>>(sum2, cnt, h1, root2, bias2, h2);

    // Layer 3 (node3 fused into cbt)
    edge23_kernel<<<512, BLK, 0, stream>>>(h2, edge_attr, src, dst, W3, b3, sum3);

    // CBT: triangular 528-block grid; recomputes h3 rows internally
    cbt_kernel<<<528, BLK, 0, stream>>>(sum3, cnt, h2, root3, bias3, (float*)d_out);
}

// Round 5
// 178.870 us; speedup vs baseline: 1.0099x; 1.0010x over previous
//
#include <hip/hip_runtime.h>

#define N_NODES 2048
#define N_EDGES 65536
#define NV 6
#define C 32
#define BLK 256

// ---------------------------------------------------------------------------
// R19 = R16 (measured 167.2) + node3 folded into cbt, REGISTER-LIGHT.
// Unified theory of R15/R17/R18 (+12..13 us each): every restructure created
// a spill cliff via aggressive unrolling (R15/R17: extra live state across
// edge23's group loop at ~190 VGPR; R18: unroll-8 recompute with 128
// hoistable float4 loads in cbt). Fix here: recompute h3 rows strictly
// sequentially -- 16 x (one row,col element), #pragma unroll 1, ~1 float4
// live. Everything else byte-identical to R16.
// ws layout (floats): cnt[2048] | sum1|sum2|sum3 [65536 each] | h1|h2.
// Locked-in lessons (all measured):
//   - atomic scatter > CSR/msg/gather structures (R3 +100, R9 +28, R12 +43)
//   - cooperative grid.sync ~50us each on 8 XCDs -> mega-kernel +365 (R7)
//   - reg-W core needs its natural ~190 VGPR; capping to 3 waves spills (R11)
//   - split-i duplicates per-edge fixed costs, +9.2 us (R14)
//   - edge23 tail restructures: R15 +12, R17 +13 -- FROZEN
//   - unroll-heavy cbt recompute: R18 +12 (spill) -- recompute must be serial
//   - cbt-sym + node-f4: neutral (R16), kept at no cost
// ---------------------------------------------------------------------------

// Layer 1 (in_c = 1), degree count fused (o==0 lane), sum2/3 zeroing fused.
__global__ void edge1_kernel(const float* __restrict__ x,
                             const float* __restrict__ ea,
                             const int* __restrict__ src,
                             const int* __restrict__ dst,
                             const float* __restrict__ W1,
                             const float* __restrict__ b1,
                             float* __restrict__ sum1,
                             float* __restrict__ sum23,   // sum2 base (2*N*C floats)
                             float* __restrict__ cnt) {
    int t = blockIdx.x * blockDim.x + threadIdx.x;
    if (t < 2 * N_NODES * C) sum23[t] = 0.0f;   // zero sum2+sum3
    int e = t >> 5, o = t & 31;
    if (e >= N_EDGES) return;
    const float* eap = ea + e * NV;
    float w = b1[o];
#pragma unroll
    for (int v = 0; v < NV; v++) w = fmaf(eap[v], W1[v * C + o], w);
    w = fmaxf(w, 0.0f);
    int d = dst[e];
    atomicAdd(&sum1[d * C + o], x[src[e]] * w);
    if (o == 0) atomicAdd(&cnt[d], 1.0f);
}

// Finalize a layer: h_out = relu(sum/max(cnt,1) + h_prev @ root + bias)
template <int IN_C>
__global__ void node_kernel(const float* __restrict__ sum,
                            const float* __restrict__ cnt,
                            const float* __restrict__ hprev,
                            const float* __restrict__ root,  // [IN_C, C]
                            const float* __restrict__ bias,  // [C]
                            float* __restrict__ hout) {
    int t = blockIdx.x * blockDim.x + threadIdx.x;  // N*C threads
    int n = t >> 5, o = t & 31;
    float inv = 1.0f / fmaxf(cnt[n], 1.0f);
    float acc = sum[t] * inv + bias[o];
    if constexpr (IN_C == 1) {
        acc = fmaf(hprev[n], root[o], acc);
    } else {
        const float4* hp4 = (const float4*)(hprev + n * IN_C);
#pragma unroll
        for (int q = 0; q < IN_C / 4; q++) {
            float4 hv = hp4[q];
            acc = fmaf(hv.x, root[(q * 4 + 0) * C + o], acc);
            acc = fmaf(hv.y, root[(q * 4 + 1) * C + o], acc);
            acc = fmaf(hv.z, root[(q * 4 + 2) * C + o], acc);
            acc = fmaf(hv.w, root[(q * 4 + 3) * C + o], acc);
        }
    }
    hout[t] = fmaxf(acc, 0.0f);
}

// Layers 2/3: EXACT R10/R13/R16 measured-best body (FROZEN -- see header).
__global__ __launch_bounds__(BLK, 2) void edge23_kernel(
    const float* __restrict__ hprev,   // [N, 32]
    const float* __restrict__ ea,      // [E, 6]
    const int* __restrict__ src,
    const int* __restrict__ dst,
    const float* __restrict__ W,       // [NV, 1024]
    const float* __restrict__ b,       // [1024]
    float* __restrict__ sumout)        // [N, 32]
{
    __shared__ float hb[4][4][256];    // [wave][group][...] = 16 KB
    const int lane = threadIdx.x & 63;
    const int o = lane & 31;
    const int half = lane >> 5;
    const int i0 = half * 16;
    const int w = threadIdx.x >> 6;

    float wreg[16][6], breg[16];
#pragma unroll
    for (int j = 0; j < 16; j++) {
#pragma unroll
        for (int v = 0; v < 6; v++) wreg[j][v] = W[v * 1024 + (i0 + j) * C + o];
        breg[j] = b[(i0 + j) * C + o];
    }

    const int wid = (blockIdx.x * BLK + threadIdx.x) >> 6;  // 0..2047

    // ---- stage h[src] for all 4 groups up front ----
    int4 sqs[4];
#pragma unroll
    for (int i = 0; i < 4; i++)
        sqs[i] = *(const int4*)&src[(wid + i * 2048) * 8 + half * 4];
#pragma unroll
    for (int i = 0; i < 4; i++) {
        float4 hq;
        hq.x = hprev[sqs[i].x * C + o];
        hq.y = hprev[sqs[i].y * C + o];
        hq.z = hprev[sqs[i].z * C + o];
        hq.w = hprev[sqs[i].w * C + o];
        *(float4*)&hb[w][i][half * 128 + o * 4] = hq;  // contiguous 1KB wave write
    }

#pragma unroll 2
    for (int i = 0; i < 4; i++) {
        const int e0 = (wid + i * 2048) * 8;
        const float* hbw = &hb[w][i][0];
        const float4* eap4 = (const float4*)(ea + (size_t)e0 * NV);
        float accs[8];
#pragma unroll
        for (int sub = 0; sub < 2; sub++) {
            float eaf[24];
#pragma unroll
            for (int t = 0; t < 6; t++) *(float4*)&eaf[t * 4] = eap4[sub * 6 + t];
            float a0 = 0.0f, a1 = 0.0f, a2 = 0.0f, a3 = 0.0f;
#pragma unroll
            for (int j = 0; j < 16; j++) {
                const float4 hA = *(const float4*)&hbw[sub * 128 + (i0 + j) * 4];
                const float bb = breg[j];
                const float w0 = wreg[j][0], w1 = wreg[j][1], w2 = wreg[j][2];
                const float w3 = wreg[j][3], w4 = wreg[j][4], w5 = wreg[j][5];
                float t0 = bb, t1 = bb, t2 = bb, t3 = bb;
                t0 = fmaf(eaf[0],  w0, t0); t1 = fmaf(eaf[6],  w0, t1);
                t2 = fmaf(eaf[12], w0, t2); t3 = fmaf(eaf[18], w0, t3);
                t0 = fmaf(eaf[1],  w1, t0); t1 = fmaf(eaf[7],  w1, t1);
                t2 = fmaf(eaf[13], w1, t2); t3 = fmaf(eaf[19], w1, t3);
                t0 = fmaf(eaf[2],  w2, t0); t1 = fmaf(eaf[8],  w2, t1);
                t2 = fmaf(eaf[14], w2, t2); t3 = fmaf(eaf[20], w2, t3);
                t0 = fmaf(eaf[3],  w3, t0); t1 = fmaf(eaf[9],  w3, t1);
                t2 = fmaf(eaf[15], w3, t2); t3 = fmaf(eaf[21], w3, t3);
                t0 = fmaf(eaf[4],  w4, t0); t1 = fmaf(eaf[10], w4, t1);
                t2 = fmaf(eaf[16], w4, t2); t3 = fmaf(eaf[22], w4, t3);
                t0 = fmaf(eaf[5],  w5, t0); t1 = fmaf(eaf[11], w5, t1);
                t2 = fmaf(eaf[17], w5, t2); t3 = fmaf(eaf[23], w5, t3);
                a0 = fmaf(hA.x, fmaxf(t0, 0.0f), a0);
                a1 = fmaf(hA.y, fmaxf(t1, 0.0f), a1);
                a2 = fmaf(hA.z, fmaxf(t2, 0.0f), a2);
                a3 = fmaf(hA.w, fmaxf(t3, 0.0f), a3);
            }
            accs[sub * 4 + 0] = a0; accs[sub * 4 + 1] = a1;
            accs[sub * 4 + 2] = a2; accs[sub * 4 + 3] = a3;
        }
#pragma unroll
        for (int k = 0; k < 8; k++) accs[k] += __shfl_down(accs[k], 32);

        const int4 dA = *(const int4*)&dst[e0];
        const int4 dB = *(const int4*)&dst[e0 + 4];
        if (lane < 32) {
            atomicAdd(&sumout[dA.x * C + o], accs[0]);
            atomicAdd(&sumout[dA.y * C + o], accs[1]);
            atomicAdd(&sumout[dA.z * C + o], accs[2]);
            atomicAdd(&sumout[dA.w * C + o], accs[3]);
            atomicAdd(&sumout[dB.x * C + o], accs[4]);
            atomicAdd(&sumout[dB.y * C + o], accs[5]);
            atomicAdd(&sumout[dB.z * C + o], accs[6]);
            atomicAdd(&sumout[dB.w * C + o], accs[7]);
        }
    }
}

// CBT with node3 fused, register-light recompute. Grid/early-return/main
// phase identical to measured-neutral R16 cbt. Recompute: 16 strictly
// sequential iterations (unroll 1), one (row,col) element each -- live state
// is one acc + one float4. r<8 covers j-side rows, r>=8 i-side (wave-uniform
// branch). Arithmetic bit-identical to node_kernel<32>.
__global__ __launch_bounds__(BLK) void cbt_kernel(const float* __restrict__ sum3,
                                                  const float* __restrict__ cnt,
                                                  const float* __restrict__ h2,
                                                  const float* __restrict__ root3,
                                                  const float* __restrict__ bias3,
                                                  float* __restrict__ out) {
    const int bx = blockIdx.x, by = blockIdx.y;
    if (by > bx) return;                 // lower-triangle blocks: mirrored instead
    __shared__ float hj_s[64][33];
    __shared__ float hi_s[64 * 32];
    __shared__ float tile[64][65];       // +1 pad: conflict-free transposed read
    const int lane = threadIdx.x & 63;
    const int w = threadIdx.x >> 6;
    const int j0 = bx * 64;
    const int i0 = by * 64;

    // ---- recompute h3 for 64 j-rows then 64 i-rows (serial, spill-proof) ----
#pragma unroll 1
    for (int r = 0; r < 16; r++) {
        const int t = threadIdx.x + r * 256;    // 0..4095
        const int row = t >> 5;                 // 0..127
        const int o = t & 31;
        const int n = row & 63;
        const int ng = (row < 64 ? j0 : i0) + n;   // wave-uniform select
        const float inv = 1.0f / fmaxf(cnt[ng], 1.0f);
        float acc = sum3[ng * 32 + o] * inv + bias3[o];
        const float4* hp4 = (const float4*)(h2 + ng * 32);
#pragma unroll
        for (int q = 0; q < 8; q++) {
            float4 hv = hp4[q];
            acc = fmaf(hv.x, root3[(q * 4 + 0) * 32 + o], acc);
            acc = fmaf(hv.y, root3[(q * 4 + 1) * 32 + o], acc);
            acc = fmaf(hv.z, root3[(q * 4 + 2) * 32 + o], acc);
            acc = fmaf(hv.w, root3[(q * 4 + 3) * 32 + o], acc);
        }
        acc = fmaxf(acc, 0.0f);
        if (row < 64) hj_s[n][o] = acc;
        else          hi_s[n * 32 + o] = acc;
    }
    __syncthreads();

    float hj[32];
#pragma unroll
    for (int k = 0; k < 32; k++) hj[k] = hj_s[lane][k];
    const int j = j0 + lane;
#pragma unroll 4
    for (int ii = w * 16; ii < w * 16 + 16; ii++) {
        float acc = 0.0f;
#pragma unroll
        for (int k = 0; k < 32; k++) acc += fabsf(hi_s[ii * 32 + k] - hj[k]);
        out[(size_t)(i0 + ii) * N_NODES + j] = acc;
        tile[ii][lane] = acc;            // row write, lanes consecutive: no conflict
    }
    if (by == bx) return;                // diagonal tile is its own transpose
    __syncthreads();
#pragma unroll 4
    for (int k = 0; k < 16; k++) {
        const int jj = w * 16 + k;
        // out[j0+jj][i0+lane] = cbt(i0+lane, j0+jj) = tile[lane][jj]
        out[(size_t)(j0 + jj) * N_NODES + i0 + lane] = tile[lane][jj];
    }
}

extern "C" void kernel_launch(void* const* d_in, const int* in_sizes, int n_in,
                              void* d_out, int out_size, void* d_ws, size_t ws_size,
                              hipStream_t stream) {
    const float* x         = (const float*)d_in[0];
    const float* edge_attr = (const float*)d_in[1];
    const int*   edge_idx  = (const int*)d_in[2];
    const float* W1 = (const float*)d_in[3];
    const float* b1 = (const float*)d_in[4];
    const float* root1 = (const float*)d_in[5];
    const float* bias1 = (const float*)d_in[6];
    const float* W2 = (const float*)d_in[7];
    const float* b2 = (const float*)d_in[8];
    const float* root2 = (const float*)d_in[9];
    const float* bias2 = (const float*)d_in[10];
    const float* W3 = (const float*)d_in[11];
    const float* b3 = (const float*)d_in[12];
    const float* root3 = (const float*)d_in[13];
    const float* bias3 = (const float*)d_in[14];

    const int* src = edge_idx;            // row 0
    const int* dst = edge_idx + N_EDGES;  // row 1

    float* ws   = (float*)d_ws;
    float* cnt  = ws;
    float* sum1 = ws + N_NODES;
    float* sum2 = sum1 + N_NODES * C;
    float* sum3 = sum2 + N_NODES * C;
    float* h1   = sum3 + N_NODES * C;
    float* h2   = h1 + N_NODES * C;

    // zero cnt + sum1 only (270 KB); sum2/sum3 zeroed inside edge1
    hipMemsetAsync(d_ws, 0, (size_t)(N_NODES + N_NODES * C) * sizeof(float), stream);

    // Layer 1 (degree count + sum2/3 zeroing fused)
    edge1_kernel<<<(N_EDGES * C) / BLK, BLK, 0, stream>>>(x, edge_attr, src, dst,
                                                          W1, b1, sum1, sum2, cnt);
    node_kernel<1><<<(N_NODES * C) / BLK, BLK, 0, stream>>>(sum1, cnt, x, root1, bias1, h1);

    // Layer 2
    edge23_kernel<<<512, BLK, 0, stream>>>(h1, edge_attr, src, dst, W2, b2, sum2);
    node_kernel<C><<<(N_NODES * C) / BLK, BLK, 0, stream>>>(sum2, cnt, h1, root2, bias2, h2);

    // Layer 3 (node3 fused into cbt)
    edge23_kernel<<<512, BLK, 0, stream>>>(h2, edge_attr, src, dst, W3, b3, sum3);

    // CBT: recomputes h3 rows internally (register-light serial recompute)
    cbt_kernel<<<dim3(N_NODES / 64, N_NODES / 64), BLK, 0, stream>>>(
        sum3, cnt, h2, root3, bias3, (float*)d_out);
}

// Round 6
// 166.708 us; speedup vs baseline: 1.0836x; 1.0730x over previous
//
#include <hip/hip_runtime.h>

#define N_NODES 2048
#define N_EDGES 65536
#define NV 6
#define C 32
#define BLK 256

// ---------------------------------------------------------------------------
// R20 = CONTROL: byte-identical resubmission of R16 (measured 167.2 us at
// round 2). Four structurally unrelated changes (R15/R17/R18/R19) each
// measured +12 us; this rerun disambiguates real regression vs bimodal
// measurement (container state H1 / co-compilation regalloc coupling H2).
// Pre-committed: ~167 => regressions real, R16 is the converged optimum;
// ~179 => +/-12 is environmental, re-rank structurally next round.
// ws layout (floats): cnt[2048] | sum1|sum2|sum3 [65536 each] | h1|h2|h3.
// Locked-in lessons (all measured):
//   - atomic scatter > CSR/msg/gather structures (R3 +100, R9 +28, R12 +43)
//   - cooperative grid.sync ~50us each on 8 XCDs -> mega-kernel +365 (R7)
//   - reg-W core needs its natural ~190 VGPR; capping to 3 waves spills (R11)
//   - split-i duplicates per-edge fixed costs, +9.2 us (R14)
// ---------------------------------------------------------------------------

// Layer 1 (in_c = 1), degree count fused (o==0 lane), sum2/3 zeroing fused.
__global__ void edge1_kernel(const float* __restrict__ x,
                             const float* __restrict__ ea,
                             const int* __restrict__ src,
                             const int* __restrict__ dst,
                             const float* __restrict__ W1,
                             const float* __restrict__ b1,
                             float* __restrict__ sum1,
                             float* __restrict__ sum23,   // sum2 base (2*N*C floats)
                             float* __restrict__ cnt) {
    int t = blockIdx.x * blockDim.x + threadIdx.x;
    if (t < 2 * N_NODES * C) sum23[t] = 0.0f;   // zero sum2+sum3
    int e = t >> 5, o = t & 31;
    if (e >= N_EDGES) return;
    const float* eap = ea + e * NV;
    float w = b1[o];
#pragma unroll
    for (int v = 0; v < NV; v++) w = fmaf(eap[v], W1[v * C + o], w);
    w = fmaxf(w, 0.0f);
    int d = dst[e];
    atomicAdd(&sum1[d * C + o], x[src[e]] * w);
    if (o == 0) atomicAdd(&cnt[d], 1.0f);
}

// Finalize a layer: h_out = relu(sum/max(cnt,1) + h_prev @ root + bias)
template <int IN_C>
__global__ void node_kernel(const float* __restrict__ sum,
                            const float* __restrict__ cnt,
                            const float* __restrict__ hprev,
                            const float* __restrict__ root,  // [IN_C, C]
                            const float* __restrict__ bias,  // [C]
                            float* __restrict__ hout) {
    int t = blockIdx.x * blockDim.x + threadIdx.x;  // N*C threads
    int n = t >> 5, o = t & 31;
    float inv = 1.0f / fmaxf(cnt[n], 1.0f);
    float acc = sum[t] * inv + bias[o];
    if constexpr (IN_C == 1) {
        acc = fmaf(hprev[n], root[o], acc);
    } else {
        const float4* hp4 = (const float4*)(hprev + n * IN_C);
#pragma unroll
        for (int q = 0; q < IN_C / 4; q++) {
            float4 hv = hp4[q];
            acc = fmaf(hv.x, root[(q * 4 + 0) * C + o], acc);
            acc = fmaf(hv.y, root[(q * 4 + 1) * C + o], acc);
            acc = fmaf(hv.z, root[(q * 4 + 2) * C + o], acc);
            acc = fmaf(hv.w, root[(q * 4 + 3) * C + o], acc);
        }
    }
    hout[t] = fmaxf(acc, 0.0f);
}

// Layers 2/3: EXACT R10/R13 measured-best body. reg-W core + up-front
// 4-group h staging; shfl_down reduce; half-wave (lane<32) atomics with dst
// loaded after the reduce (short live range -- keeps natural ~190 VGPR).
__global__ __launch_bounds__(BLK, 2) void edge23_kernel(
    const float* __restrict__ hprev,   // [N, 32]
    const float* __restrict__ ea,      // [E, 6]
    const int* __restrict__ src,
    const int* __restrict__ dst,
    const float* __restrict__ W,       // [NV, 1024]
    const float* __restrict__ b,       // [1024]
    float* __restrict__ sumout)        // [N, 32]
{
    __shared__ float hb[4][4][256];    // [wave][group][...] = 16 KB
    const int lane = threadIdx.x & 63;
    const int o = lane & 31;
    const int half = lane >> 5;
    const int i0 = half * 16;
    const int w = threadIdx.x >> 6;

    float wreg[16][6], breg[16];
#pragma unroll
    for (int j = 0; j < 16; j++) {
#pragma unroll
        for (int v = 0; v < 6; v++) wreg[j][v] = W[v * 1024 + (i0 + j) * C + o];
        breg[j] = b[(i0 + j) * C + o];
    }

    const int wid = (blockIdx.x * BLK + threadIdx.x) >> 6;  // 0..2047

    // ---- stage h[src] for all 4 groups up front ----
    int4 sqs[4];
#pragma unroll
    for (int i = 0; i < 4; i++)
        sqs[i] = *(const int4*)&src[(wid + i * 2048) * 8 + half * 4];
#pragma unroll
    for (int i = 0; i < 4; i++) {
        float4 hq;
        hq.x = hprev[sqs[i].x * C + o];
        hq.y = hprev[sqs[i].y * C + o];
        hq.z = hprev[sqs[i].z * C + o];
        hq.w = hprev[sqs[i].w * C + o];
        *(float4*)&hb[w][i][half * 128 + o * 4] = hq;  // contiguous 1KB wave write
    }

#pragma unroll 2
    for (int i = 0; i < 4; i++) {
        const int e0 = (wid + i * 2048) * 8;
        const float* hbw = &hb[w][i][0];
        const float4* eap4 = (const float4*)(ea + (size_t)e0 * NV);
        float accs[8];
#pragma unroll
        for (int sub = 0; sub < 2; sub++) {
            float eaf[24];
#pragma unroll
            for (int t = 0; t < 6; t++) *(float4*)&eaf[t * 4] = eap4[sub * 6 + t];
            float a0 = 0.0f, a1 = 0.0f, a2 = 0.0f, a3 = 0.0f;
#pragma unroll
            for (int j = 0; j < 16; j++) {
                const float4 hA = *(const float4*)&hbw[sub * 128 + (i0 + j) * 4];
                const float bb = breg[j];
                const float w0 = wreg[j][0], w1 = wreg[j][1], w2 = wreg[j][2];
                const float w3 = wreg[j][3], w4 = wreg[j][4], w5 = wreg[j][5];
                float t0 = bb, t1 = bb, t2 = bb, t3 = bb;
                t0 = fmaf(eaf[0],  w0, t0); t1 = fmaf(eaf[6],  w0, t1);
                t2 = fmaf(eaf[12], w0, t2); t3 = fmaf(eaf[18], w0, t3);
                t0 = fmaf(eaf[1],  w1, t0); t1 = fmaf(eaf[7],  w1, t1);
                t2 = fmaf(eaf[13], w1, t2); t3 = fmaf(eaf[19], w1, t3);
                t0 = fmaf(eaf[2],  w2, t0); t1 = fmaf(eaf[8],  w2, t1);
                t2 = fmaf(eaf[14], w2, t2); t3 = fmaf(eaf[20], w2, t3);
                t0 = fmaf(eaf[3],  w3, t0); t1 = fmaf(eaf[9],  w3, t1);
                t2 = fmaf(eaf[15], w3, t2); t3 = fmaf(eaf[21], w3, t3);
                t0 = fmaf(eaf[4],  w4, t0); t1 = fmaf(eaf[10], w4, t1);
                t2 = fmaf(eaf[16], w4, t2); t3 = fmaf(eaf[22], w4, t3);
                t0 = fmaf(eaf[5],  w5, t0); t1 = fmaf(eaf[11], w5, t1);
                t2 = fmaf(eaf[17], w5, t2); t3 = fmaf(eaf[23], w5, t3);
                a0 = fmaf(hA.x, fmaxf(t0, 0.0f), a0);
                a1 = fmaf(hA.y, fmaxf(t1, 0.0f), a1);
                a2 = fmaf(hA.z, fmaxf(t2, 0.0f), a2);
                a3 = fmaf(hA.w, fmaxf(t3, 0.0f), a3);
            }
            accs[sub * 4 + 0] = a0; accs[sub * 4 + 1] = a1;
            accs[sub * 4 + 2] = a2; accs[sub * 4 + 3] = a3;
        }
#pragma unroll
        for (int k = 0; k < 8; k++) accs[k] += __shfl_down(accs[k], 32);

        const int4 dA = *(const int4*)&dst[e0];
        const int4 dB = *(const int4*)&dst[e0 + 4];
        if (lane < 32) {
            atomicAdd(&sumout[dA.x * C + o], accs[0]);
            atomicAdd(&sumout[dA.y * C + o], accs[1]);
            atomicAdd(&sumout[dA.z * C + o], accs[2]);
            atomicAdd(&sumout[dA.w * C + o], accs[3]);
            atomicAdd(&sumout[dB.x * C + o], accs[4]);
            atomicAdd(&sumout[dB.y * C + o], accs[5]);
            atomicAdd(&sumout[dB.z * C + o], accs[6]);
            atomicAdd(&sumout[dB.w * C + o], accs[7]);
        }
    }
}

// CBT: out[i,j] = sum_k |h[i,k]-h[j,k]|. Symmetric: compute upper triangle
// (by <= bx) only, mirror off-diagonal tiles via LDS transpose.
__global__ __launch_bounds__(BLK) void cbt_kernel(const float* __restrict__ h,
                                                  float* __restrict__ out) {
    const int bx = blockIdx.x, by = blockIdx.y;
    if (by > bx) return;                 // lower-triangle blocks: mirrored instead
    __shared__ float hj_s[64][33];
    __shared__ float hi_s[64 * 32];
    __shared__ float tile[64][65];       // +1 pad: conflict-free transposed read
    const int lane = threadIdx.x & 63;
    const int w = threadIdx.x >> 6;
    const int j0 = bx * 64;
    const int i0 = by * 64;
    for (int t = threadIdx.x; t < 64 * 32; t += BLK) {
        hj_s[t >> 5][t & 31] = h[j0 * 32 + t];
        hi_s[t] = h[i0 * 32 + t];
    }
    __syncthreads();
    float hj[32];
#pragma unroll
    for (int k = 0; k < 32; k++) hj[k] = hj_s[lane][k];
    const int j = j0 + lane;
#pragma unroll 4
    for (int ii = w * 16; ii < w * 16 + 16; ii++) {
        float acc = 0.0f;
#pragma unroll
        for (int k = 0; k < 32; k++) acc += fabsf(hi_s[ii * 32 + k] - hj[k]);
        out[(size_t)(i0 + ii) * N_NODES + j] = acc;
        tile[ii][lane] = acc;            // row write, lanes consecutive: no conflict
    }
    if (by == bx) return;                // diagonal tile is its own transpose
    __syncthreads();
#pragma unroll 4
    for (int k = 0; k < 16; k++) {
        const int jj = w * 16 + k;
        // out[j0+jj][i0+lane] = cbt(i0+lane, j0+jj) = tile[lane][jj]
        // LDS: stride 65 between lanes -> bank = (lane+jj)%32, 2-way = free
        out[(size_t)(j0 + jj) * N_NODES + i0 + lane] = tile[lane][jj];
    }
}

extern "C" void kernel_launch(void* const* d_in, const int* in_sizes, int n_in,
                              void* d_out, int out_size, void* d_ws, size_t ws_size,
                              hipStream_t stream) {
    const float* x         = (const float*)d_in[0];
    const float* edge_attr = (const float*)d_in[1];
    const int*   edge_idx  = (const int*)d_in[2];
    const float* W1 = (const float*)d_in[3];
    const float* b1 = (const float*)d_in[4];
    const float* root1 = (const float*)d_in[5];
    const float* bias1 = (const float*)d_in[6];
    const float* W2 = (const float*)d_in[7];
    const float* b2 = (const float*)d_in[8];
    const float* root2 = (const float*)d_in[9];
    const float* bias2 = (const float*)d_in[10];
    const float* W3 = (const float*)d_in[11];
    const float* b3 = (const float*)d_in[12];
    const float* root3 = (const float*)d_in[13];
    const float* bias3 = (const float*)d_in[14];

    const int* src = edge_idx;            // row 0
    const int* dst = edge_idx + N_EDGES;  // row 1

    float* ws   = (float*)d_ws;
    float* cnt  = ws;
    float* sum1 = ws + N_NODES;
    float* sum2 = sum1 + N_NODES * C;
    float* sum3 = sum2 + N_NODES * C;
    float* h1   = sum3 + N_NODES * C;
    float* h2   = h1 + N_NODES * C;
    float* h3   = h2 + N_NODES * C;

    // zero cnt + sum1 only (270 KB); sum2/sum3 zeroed inside edge1
    hipMemsetAsync(d_ws, 0, (size_t)(N_NODES + N_NODES * C) * sizeof(float), stream);

    // Layer 1 (degree count + sum2/3 zeroing fused)
    edge1_kernel<<<(N_EDGES * C) / BLK, BLK, 0, stream>>>(x, edge_attr, src, dst,
                                                          W1, b1, sum1, sum2, cnt);
    node_kernel<1><<<(N_NODES * C) / BLK, BLK, 0, stream>>>(sum1, cnt, x, root1, bias1, h1);

    // Layer 2
    edge23_kernel<<<512, BLK, 0, stream>>>(h1, edge_attr, src, dst, W2, b2, sum2);
    node_kernel<C><<<(N_NODES * C) / BLK, BLK, 0, stream>>>(sum2, cnt, h1, root2, bias2, h2);

    // Layer 3
    edge23_kernel<<<512, BLK, 0, stream>>>(h2, edge_attr, src, dst, W3, b3, sum3);
    node_kernel<C><<<(N_NODES * C) / BLK, BLK, 0, stream>>>(sum3, cnt, h2, root3, bias3, h3);

    // CBT (symmetric: 528 upper-triangle tiles computed, 496 mirrored)
    cbt_kernel<<<dim3(N_NODES / 64, N_NODES / 64), BLK, 0, stream>>>(h3, (float*)d_out);
}

// Round 7
// 164.206 us; speedup vs baseline: 1.1001x; 1.0152x over previous
//
#include <hip/hip_runtime.h>

#define N_NODES 2048
#define N_EDGES 65536
#define NV 6
#define C 32
#define BLK 256

// ---------------------------------------------------------------------------
// R21 = R20/R16 (reproducible 166.6-167.2) + triangular cbt grid ONLY.
// Control round R20 rejected environmental bimodality: the R16 binary
// reliably runs ~167; the four +12 regressions were real. Mechanisms:
//   R15/R17: edge23 K-loop live-state/codegen flips (FROZEN zone)
//   R18/R19: cbt h3-recompute had ~33x redundancy (~300MB extra L2) -- both
//            variants paid the same traffic, register pressure was innocent
// This round's only edit: cbt launches 528 triangular blocks (sqrt decode,
// proven correct in R18/R19) instead of 1024 with 496 early-returns.
// Everything else byte-identical to R20.
// ws layout (floats): cnt[2048] | sum1|sum2|sum3 [65536 each] | h1|h2|h3.
// Locked-in lessons (all measured):
//   - atomic scatter > CSR/msg/gather structures (R3 +100, R9 +28, R12 +43)
//   - cooperative grid.sync ~50us each on 8 XCDs -> mega-kernel +365 (R7)
//   - reg-W core needs its natural ~190 VGPR; capping to 3 waves spills (R11)
//   - split-i duplicates per-edge fixed costs, +9.2 us (R14)
//   - edge23 K-loop edits: R15 +12, R17 +13 -- FROZEN
//   - fusion with recompute redundancy: R18/R19 +12 -- only fuse 1:1 work
//   - cbt-sym + node-f4: neutral (R16), kept at no cost
// ---------------------------------------------------------------------------

// Layer 1 (in_c = 1), degree count fused (o==0 lane), sum2/3 zeroing fused.
__global__ void edge1_kernel(const float* __restrict__ x,
                             const float* __restrict__ ea,
                             const int* __restrict__ src,
                             const int* __restrict__ dst,
                             const float* __restrict__ W1,
                             const float* __restrict__ b1,
                             float* __restrict__ sum1,
                             float* __restrict__ sum23,   // sum2 base (2*N*C floats)
                             float* __restrict__ cnt) {
    int t = blockIdx.x * blockDim.x + threadIdx.x;
    if (t < 2 * N_NODES * C) sum23[t] = 0.0f;   // zero sum2+sum3
    int e = t >> 5, o = t & 31;
    if (e >= N_EDGES) return;
    const float* eap = ea + e * NV;
    float w = b1[o];
#pragma unroll
    for (int v = 0; v < NV; v++) w = fmaf(eap[v], W1[v * C + o], w);
    w = fmaxf(w, 0.0f);
    int d = dst[e];
    atomicAdd(&sum1[d * C + o], x[src[e]] * w);
    if (o == 0) atomicAdd(&cnt[d], 1.0f);
}

// Finalize a layer: h_out = relu(sum/max(cnt,1) + h_prev @ root + bias)
template <int IN_C>
__global__ void node_kernel(const float* __restrict__ sum,
                            const float* __restrict__ cnt,
                            const float* __restrict__ hprev,
                            const float* __restrict__ root,  // [IN_C, C]
                            const float* __restrict__ bias,  // [C]
                            float* __restrict__ hout) {
    int t = blockIdx.x * blockDim.x + threadIdx.x;  // N*C threads
    int n = t >> 5, o = t & 31;
    float inv = 1.0f / fmaxf(cnt[n], 1.0f);
    float acc = sum[t] * inv + bias[o];
    if constexpr (IN_C == 1) {
        acc = fmaf(hprev[n], root[o], acc);
    } else {
        const float4* hp4 = (const float4*)(hprev + n * IN_C);
#pragma unroll
        for (int q = 0; q < IN_C / 4; q++) {
            float4 hv = hp4[q];
            acc = fmaf(hv.x, root[(q * 4 + 0) * C + o], acc);
            acc = fmaf(hv.y, root[(q * 4 + 1) * C + o], acc);
            acc = fmaf(hv.z, root[(q * 4 + 2) * C + o], acc);
            acc = fmaf(hv.w, root[(q * 4 + 3) * C + o], acc);
        }
    }
    hout[t] = fmaxf(acc, 0.0f);
}

// Layers 2/3: EXACT R10/R13 measured-best body (FROZEN -- see header).
__global__ __launch_bounds__(BLK, 2) void edge23_kernel(
    const float* __restrict__ hprev,   // [N, 32]
    const float* __restrict__ ea,      // [E, 6]
    const int* __restrict__ src,
    const int* __restrict__ dst,
    const float* __restrict__ W,       // [NV, 1024]
    const float* __restrict__ b,       // [1024]
    float* __restrict__ sumout)        // [N, 32]
{
    __shared__ float hb[4][4][256];    // [wave][group][...] = 16 KB
    const int lane = threadIdx.x & 63;
    const int o = lane & 31;
    const int half = lane >> 5;
    const int i0 = half * 16;
    const int w = threadIdx.x >> 6;

    float wreg[16][6], breg[16];
#pragma unroll
    for (int j = 0; j < 16; j++) {
#pragma unroll
        for (int v = 0; v < 6; v++) wreg[j][v] = W[v * 1024 + (i0 + j) * C + o];
        breg[j] = b[(i0 + j) * C + o];
    }

    const int wid = (blockIdx.x * BLK + threadIdx.x) >> 6;  // 0..2047

    // ---- stage h[src] for all 4 groups up front ----
    int4 sqs[4];
#pragma unroll
    for (int i = 0; i < 4; i++)
        sqs[i] = *(const int4*)&src[(wid + i * 2048) * 8 + half * 4];
#pragma unroll
    for (int i = 0; i < 4; i++) {
        float4 hq;
        hq.x = hprev[sqs[i].x * C + o];
        hq.y = hprev[sqs[i].y * C + o];
        hq.z = hprev[sqs[i].z * C + o];
        hq.w = hprev[sqs[i].w * C + o];
        *(float4*)&hb[w][i][half * 128 + o * 4] = hq;  // contiguous 1KB wave write
    }

#pragma unroll 2
    for (int i = 0; i < 4; i++) {
        const int e0 = (wid + i * 2048) * 8;
        const float* hbw = &hb[w][i][0];
        const float4* eap4 = (const float4*)(ea + (size_t)e0 * NV);
        float accs[8];
#pragma unroll
        for (int sub = 0; sub < 2; sub++) {
            float eaf[24];
#pragma unroll
            for (int t = 0; t < 6; t++) *(float4*)&eaf[t * 4] = eap4[sub * 6 + t];
            float a0 = 0.0f, a1 = 0.0f, a2 = 0.0f, a3 = 0.0f;
#pragma unroll
            for (int j = 0; j < 16; j++) {
                const float4 hA = *(const float4*)&hbw[sub * 128 + (i0 + j) * 4];
                const float bb = breg[j];
                const float w0 = wreg[j][0], w1 = wreg[j][1], w2 = wreg[j][2];
                const float w3 = wreg[j][3], w4 = wreg[j][4], w5 = wreg[j][5];
                float t0 = bb, t1 = bb, t2 = bb, t3 = bb;
                t0 = fmaf(eaf[0],  w0, t0); t1 = fmaf(eaf[6],  w0, t1);
                t2 = fmaf(eaf[12], w0, t2); t3 = fmaf(eaf[18], w0, t3);
                t0 = fmaf(eaf[1],  w1, t0); t1 = fmaf(eaf[7],  w1, t1);
                t2 = fmaf(eaf[13], w1, t2); t3 = fmaf(eaf[19], w1, t3);
                t0 = fmaf(eaf[2],  w2, t0); t1 = fmaf(eaf[8],  w2, t1);
                t2 = fmaf(eaf[14], w2, t2); t3 = fmaf(eaf[20], w2, t3);
                t0 = fmaf(eaf[3],  w3, t0); t1 = fmaf(eaf[9],  w3, t1);
                t2 = fmaf(eaf[15], w3, t2); t3 = fmaf(eaf[21], w3, t3);
                t0 = fmaf(eaf[4],  w4, t0); t1 = fmaf(eaf[10], w4, t1);
                t2 = fmaf(eaf[16], w4, t2); t3 = fmaf(eaf[22], w4, t3);
                t0 = fmaf(eaf[5],  w5, t0); t1 = fmaf(eaf[11], w5, t1);
                t2 = fmaf(eaf[17], w5, t2); t3 = fmaf(eaf[23], w5, t3);
                a0 = fmaf(hA.x, fmaxf(t0, 0.0f), a0);
                a1 = fmaf(hA.y, fmaxf(t1, 0.0f), a1);
                a2 = fmaf(hA.z, fmaxf(t2, 0.0f), a2);
                a3 = fmaf(hA.w, fmaxf(t3, 0.0f), a3);
            }
            accs[sub * 4 + 0] = a0; accs[sub * 4 + 1] = a1;
            accs[sub * 4 + 2] = a2; accs[sub * 4 + 3] = a3;
        }
#pragma unroll
        for (int k = 0; k < 8; k++) accs[k] += __shfl_down(accs[k], 32);

        const int4 dA = *(const int4*)&dst[e0];
        const int4 dB = *(const int4*)&dst[e0 + 4];
        if (lane < 32) {
            atomicAdd(&sumout[dA.x * C + o], accs[0]);
            atomicAdd(&sumout[dA.y * C + o], accs[1]);
            atomicAdd(&sumout[dA.z * C + o], accs[2]);
            atomicAdd(&sumout[dA.w * C + o], accs[3]);
            atomicAdd(&sumout[dB.x * C + o], accs[4]);
            atomicAdd(&sumout[dB.y * C + o], accs[5]);
            atomicAdd(&sumout[dB.z * C + o], accs[6]);
            atomicAdd(&sumout[dB.w * C + o], accs[7]);
        }
    }
}

// CBT: out[i,j] = sum_k |h[i,k]-h[j,k]|. Symmetric upper triangle, mirrored
// via LDS transpose. R21: triangular 528-block grid (sqrt decode, proven in
// R18/R19) -- no 496 early-return blocks. Body identical to R16/R20.
__global__ __launch_bounds__(BLK) void cbt_kernel(const float* __restrict__ h,
                                                  float* __restrict__ out) {
    const int L = blockIdx.x;
    int bx = (int)((sqrtf(8.0f * L + 1.0f) - 1.0f) * 0.5f);
    while ((bx + 1) * (bx + 2) / 2 <= L) bx++;
    while (bx * (bx + 1) / 2 > L) bx--;
    const int by = L - bx * (bx + 1) / 2;   // by <= bx

    __shared__ float hj_s[64][33];
    __shared__ float hi_s[64 * 32];
    __shared__ float tile[64][65];       // +1 pad: conflict-free transposed read
    const int lane = threadIdx.x & 63;
    const int w = threadIdx.x >> 6;
    const int j0 = bx * 64;
    const int i0 = by * 64;
    for (int t = threadIdx.x; t < 64 * 32; t += BLK) {
        hj_s[t >> 5][t & 31] = h[j0 * 32 + t];
        hi_s[t] = h[i0 * 32 + t];
    }
    __syncthreads();
    float hj[32];
#pragma unroll
    for (int k = 0; k < 32; k++) hj[k] = hj_s[lane][k];
    const int j = j0 + lane;
#pragma unroll 4
    for (int ii = w * 16; ii < w * 16 + 16; ii++) {
        float acc = 0.0f;
#pragma unroll
        for (int k = 0; k < 32; k++) acc += fabsf(hi_s[ii * 32 + k] - hj[k]);
        out[(size_t)(i0 + ii) * N_NODES + j] = acc;
        tile[ii][lane] = acc;            // row write, lanes consecutive: no conflict
    }
    if (by == bx) return;                // diagonal tile is its own transpose
    __syncthreads();
#pragma unroll 4
    for (int k = 0; k < 16; k++) {
        const int jj = w * 16 + k;
        // out[j0+jj][i0+lane] = cbt(i0+lane, j0+jj) = tile[lane][jj]
        // LDS: stride 65 between lanes -> bank = (lane+jj)%32, 2-way = free
        out[(size_t)(j0 + jj) * N_NODES + i0 + lane] = tile[lane][jj];
    }
}

extern "C" void kernel_launch(void* const* d_in, const int* in_sizes, int n_in,
                              void* d_out, int out_size, void* d_ws, size_t ws_size,
                              hipStream_t stream) {
    const float* x         = (const float*)d_in[0];
    const float* edge_attr = (const float*)d_in[1];
    const int*   edge_idx  = (const int*)d_in[2];
    const float* W1 = (const float*)d_in[3];
    const float* b1 = (const float*)d_in[4];
    const float* root1 = (const float*)d_in[5];
    const float* bias1 = (const float*)d_in[6];
    const float* W2 = (const float*)d_in[7];
    const float* b2 = (const float*)d_in[8];
    const float* root2 = (const float*)d_in[9];
    const float* bias2 = (const float*)d_in[10];
    const float* W3 = (const float*)d_in[11];
    const float* b3 = (const float*)d_in[12];
    const float* root3 = (const float*)d_in[13];
    const float* bias3 = (const float*)d_in[14];

    const int* src = edge_idx;            // row 0
    const int* dst = edge_idx + N_EDGES;  // row 1

    float* ws   = (float*)d_ws;
    float* cnt  = ws;
    float* sum1 = ws + N_NODES;
    float* sum2 = sum1 + N_NODES * C;
    float* sum3 = sum2 + N_NODES * C;
    float* h1   = sum3 + N_NODES * C;
    float* h2   = h1 + N_NODES * C;
    float* h3   = h2 + N_NODES * C;

    // zero cnt + sum1 only (270 KB); sum2/sum3 zeroed inside edge1
    hipMemsetAsync(d_ws, 0, (size_t)(N_NODES + N_NODES * C) * sizeof(float), stream);

    // Layer 1 (degree count + sum2/3 zeroing fused)
    edge1_kernel<<<(N_EDGES * C) / BLK, BLK, 0, stream>>>(x, edge_attr, src, dst,
                                                          W1, b1, sum1, sum2, cnt);
    node_kernel<1><<<(N_NODES * C) / BLK, BLK, 0, stream>>>(sum1, cnt, x, root1, bias1, h1);

    // Layer 2
    edge23_kernel<<<512, BLK, 0, stream>>>(h1, edge_attr, src, dst, W2, b2, sum2);
    node_kernel<C><<<(N_NODES * C) / BLK, BLK, 0, stream>>>(sum2, cnt, h1, root2, bias2, h2);

    // Layer 3
    edge23_kernel<<<512, BLK, 0, stream>>>(h2, edge_attr, src, dst, W3, b3, sum3);
    node_kernel<C><<<(N_NODES * C) / BLK, BLK, 0, stream>>>(sum3, cnt, h2, root3, bias3, h3);

    // CBT (triangular: 528 blocks, 528 computed tiles, 496 mirrored)
    cbt_kernel<<<528, BLK, 0, stream>>>(h3, (float*)d_out);
}